// Round 1
// baseline (504.852 us; speedup 1.0000x reference)
//
#include <hip/hip_runtime.h>
#include <hip/hip_bf16.h>
#include <stdint.h>

// Problem constants
#define NH 12
#define DHD 64
#define DM 768
#define NB 2
#define SS 4096
#define MTOK 8192  // NB*SS

typedef __attribute__((ext_vector_type(8))) short short8;
typedef __attribute__((ext_vector_type(4))) float f32x4;
typedef __attribute__((ext_vector_type(4))) unsigned short ushort4v;

#define MFMA(a, b, c) __builtin_amdgcn_mfma_f32_16x16x32_bf16(a, b, c, 0, 0, 0)
#define LOG2E 1.4426950408889634f

static __device__ __forceinline__ unsigned short f2bf(float f) {
  union { float f; unsigned int u; } c; c.f = f;
  unsigned int r = (c.u + 0x7FFFu + ((c.u >> 16) & 1u)) >> 16;
  return (unsigned short)r;
}

static __device__ __forceinline__ void gld_lds16(const void* g, void* l) {
  __builtin_amdgcn_global_load_lds(
      (const __attribute__((address_space(1))) unsigned int*)g,
      (__attribute__((address_space(3))) unsigned int*)l, 16, 0, 0);
}

// ---------------- conversion kernels ----------------

__global__ void convert_x(const float* __restrict__ x, unsigned short* __restrict__ xb, int n4) {
  int i = blockIdx.x * blockDim.x + threadIdx.x;
  int stride = gridDim.x * blockDim.x;
  for (; i < n4; i += stride) {
    float4 v = ((const float4*)x)[i];
    ushort4v o;
    o[0] = f2bf(v.x); o[1] = f2bf(v.y); o[2] = f2bf(v.z); o[3] = f2bf(v.w);
    ((ushort4v*)xb)[i] = o;
  }
}

// W[k][n] fp32 -> WT[n][k] bf16 (LDS-tiled transpose)
__global__ void wtrans(const float* __restrict__ W, unsigned short* __restrict__ WT) {
  __shared__ float t[32][33];
  int tx = threadIdx.x, ty = threadIdx.y;
  int bx = blockIdx.x * 32, by = blockIdx.y * 32;
#pragma unroll
  for (int k = 0; k < 4; k++) t[ty + 8 * k][tx] = W[(size_t)(by + ty + 8 * k) * DM + bx + tx];
  __syncthreads();
#pragma unroll
  for (int k = 0; k < 4; k++)
    WT[(size_t)(bx + ty + 8 * k) * DM + by + tx] = f2bf(t[tx][ty + 8 * k]);
}

// ---------------- GEMM: C[M=8192][N=768] = A[8192][768] @ BT[n][k]^T + bias ----------------
// MODE 0: Q out bf16 [(b*12+h)*4096+s][64], scaled by 0.125
// MODE 1: K out bf16 same layout
// MODE 2: V out bf16 transposed [(b*12+h)*64+d][4096]
// MODE 3: fp32 out [m][768] (final output)

template <int MODE>
__global__ __launch_bounds__(256, 2) void gemm128(const unsigned short* __restrict__ A,
                                                  const unsigned short* __restrict__ BT,
                                                  const float* __restrict__ bias,
                                                  void* __restrict__ out) {
  __shared__ unsigned short As[128 * 32];
  __shared__ unsigned short Bs[128 * 32];
  const int tid = threadIdx.x;
  const int wave = tid >> 6, lane = tid & 63;
  const int qd = lane >> 4, r = lane & 15;
  const int bm = blockIdx.x, bn = blockIdx.y;
  const int wr = (wave >> 1) * 64, wc = (wave & 1) * 64;

  f32x4 acc[4][4] = {};

  for (int k0 = 0; k0 < DM; k0 += 32) {
    __syncthreads();
#pragma unroll
    for (int p = 0; p < 2; p++) {
      int g = (wave * 2 + p) * 64 + lane;
      int row = g >> 2, ko = (g & 3) << 3;
      gld_lds16(A + (size_t)(bm * 128 + row) * DM + k0 + ko, &As[(wave * 2 + p) * 512]);
      gld_lds16(BT + (size_t)(bn * 128 + row) * DM + k0 + ko, &Bs[(wave * 2 + p) * 512]);
    }
    __syncthreads();

    short8 af[4], bfr[4];
#pragma unroll
    for (int mi = 0; mi < 4; mi++) af[mi] = *(const short8*)&As[(wr + mi * 16 + r) * 32 + qd * 8];
#pragma unroll
    for (int ni = 0; ni < 4; ni++) bfr[ni] = *(const short8*)&Bs[(wc + ni * 16 + r) * 32 + qd * 8];
#pragma unroll
    for (int mi = 0; mi < 4; mi++)
#pragma unroll
      for (int ni = 0; ni < 4; ni++) acc[mi][ni] = MFMA(af[mi], bfr[ni], acc[mi][ni]);
  }

#pragma unroll
  for (int ni = 0; ni < 4; ni++) {
    int n = bn * 128 + wc + ni * 16 + r;
    float bv = bias[n];
#pragma unroll
    for (int mi = 0; mi < 4; mi++) {
      int m0 = bm * 128 + wr + mi * 16 + qd * 4;
      f32x4 v = acc[mi][ni];
      if (MODE == 3) {
        float* O = (float*)out;
#pragma unroll
        for (int i = 0; i < 4; i++) O[(size_t)(m0 + i) * DM + n] = v[i] + bv;
      } else if (MODE == 2) {
        unsigned short* O = (unsigned short*)out;
        int h = n >> 6, d = n & 63;
        int b = m0 >> 12, s = m0 & 4095;
        ushort4v pk;
        pk[0] = f2bf(v[0] + bv); pk[1] = f2bf(v[1] + bv);
        pk[2] = f2bf(v[2] + bv); pk[3] = f2bf(v[3] + bv);
        *(ushort4v*)&O[((size_t)((b * NH + h) * DHD + d)) * SS + s] = pk;
      } else {
        unsigned short* O = (unsigned short*)out;
        int h = n >> 6, d = n & 63;
        const float sc = (MODE == 0) ? 0.125f : 1.0f;
#pragma unroll
        for (int i = 0; i < 4; i++) {
          int m = m0 + i, b = m >> 12, s = m & 4095;
          O[((size_t)((b * NH + h) * SS + s)) * DHD + d] = f2bf((v[i] + bv) * sc);
        }
      }
    }
  }
}

// ---------------- flash attention ----------------
// Q,K: [(b*H+h)*S + s][64] bf16 (Q pre-scaled by 0.125); VT: [(b*H+h)*64 + d][S] bf16
// ctx out: [b*S+s][768] bf16
__global__ __launch_bounds__(256, 2) void attn(const unsigned short* __restrict__ Q,
                                               const unsigned short* __restrict__ K,
                                               const unsigned short* __restrict__ VT,
                                               unsigned short* __restrict__ ctx) {
  // LDS: P region (4 waves x [32][136] = 17408 ushorts, K-tile [128][72]=9216 overlays it)
  //      V region [64][136] = 8704 ushorts
  __shared__ unsigned short sh[26112];  // 52224 B
  unsigned short* Ks = sh;
  unsigned short* Vs = sh + 17408;
  const int tid = threadIdx.x;
  const int wave = tid >> 6, lane = tid & 63;
  const int qd = lane >> 4, r = lane & 15;
  unsigned short* Pl = sh + wave * 4352;  // [32][136] per wave

  const int qt = blockIdx.x, h = blockIdx.y, b = blockIdx.z;
  const int bh = b * NH + h;
  const unsigned short* Qh = Q + (size_t)bh * SS * DHD;
  const unsigned short* Kh = K + (size_t)bh * SS * DHD;
  const unsigned short* Vh = VT + (size_t)bh * DHD * SS;
  const int q0 = qt * 128 + wave * 32;

  short8 qa[2][2];
#pragma unroll
  for (int mt = 0; mt < 2; mt++)
#pragma unroll
    for (int kc = 0; kc < 2; kc++)
      qa[mt][kc] = *(const short8*)&Qh[(size_t)(q0 + mt * 16 + r) * DHD + kc * 32 + qd * 8];

  float mrun[2][4], lrun[2][4];
  f32x4 oacc[2][4] = {};
#pragma unroll
  for (int mt = 0; mt < 2; mt++)
#pragma unroll
    for (int i = 0; i < 4; i++) { mrun[mt][i] = -1e30f; lrun[mt][i] = 0.f; }

  for (int kv = 0; kv < SS; kv += 128) {
    __syncthreads();
    // stage K tile [128][64] -> Ks[128][72]
#pragma unroll
    for (int p = 0; p < 4; p++) {
      int c = p * 256 + tid;
      int key = c >> 3, dc = (c & 7) * 8;
      uint4 vv = *(const uint4*)&Kh[(size_t)(kv + key) * DHD + dc];
      *(uint4*)&Ks[key * 72 + dc] = vv;
    }
    // stage V^T tile [64][128] -> Vs[64][136]
#pragma unroll
    for (int p = 0; p < 4; p++) {
      int c = p * 256 + tid;
      int d = c >> 4, kc8 = (c & 15) * 8;
      uint4 vv = *(const uint4*)&Vh[(size_t)d * SS + kv + kc8];
      *(uint4*)&Vs[d * 136 + kc8] = vv;
    }
    __syncthreads();

    // S = Q K^T   (rows 4*qd+i per lane, col = r + nt*16)
    f32x4 sacc[2][8] = {};
#pragma unroll
    for (int mt = 0; mt < 2; mt++)
#pragma unroll
      for (int nt = 0; nt < 8; nt++)
#pragma unroll
        for (int kc = 0; kc < 2; kc++)
          sacc[mt][nt] = MFMA(qa[mt][kc],
                              *(const short8*)&Ks[(nt * 16 + r) * 72 + kc * 32 + qd * 8],
                              sacc[mt][nt]);

    // online softmax (fp32)
    float scl[2][4];
#pragma unroll
    for (int mt = 0; mt < 2; mt++)
#pragma unroll
      for (int i = 0; i < 4; i++) {
        float mx = sacc[mt][0][i];
#pragma unroll
        for (int nt = 1; nt < 8; nt++) mx = fmaxf(mx, sacc[mt][nt][i]);
#pragma unroll
        for (int sft = 1; sft < 16; sft <<= 1) mx = fmaxf(mx, __shfl_xor(mx, sft, 64));
        float mn = fmaxf(mrun[mt][i], mx);
        float sc = exp2f((mrun[mt][i] - mn) * LOG2E);
        mrun[mt][i] = mn;
        scl[mt][i] = sc;
        float rs = 0.f;
#pragma unroll
        for (int nt = 0; nt < 8; nt++) {
          float p = exp2f((sacc[mt][nt][i] - mn) * LOG2E);
          sacc[mt][nt][i] = p;
          rs += p;
        }
#pragma unroll
        for (int sft = 1; sft < 16; sft <<= 1) rs += __shfl_xor(rs, sft, 64);
        lrun[mt][i] = lrun[mt][i] * sc + rs;
      }

    __syncthreads();  // all waves done reading Ks before P overlays it

    // write P (bf16) to per-wave LDS [32][136]
#pragma unroll
    for (int mt = 0; mt < 2; mt++)
#pragma unroll
      for (int nt = 0; nt < 8; nt++)
#pragma unroll
        for (int i = 0; i < 4; i++)
          Pl[(mt * 16 + qd * 4 + i) * 136 + nt * 16 + r] = f2bf(sacc[mt][nt][i]);

    // rescale O
#pragma unroll
    for (int mt = 0; mt < 2; mt++)
#pragma unroll
      for (int dn = 0; dn < 4; dn++)
#pragma unroll
        for (int i = 0; i < 4; i++) oacc[mt][dn][i] *= scl[mt][i];

    // O += P @ V
#pragma unroll
    for (int mt = 0; mt < 2; mt++)
#pragma unroll
      for (int dn = 0; dn < 4; dn++)
#pragma unroll
        for (int kc = 0; kc < 4; kc++)
          oacc[mt][dn] = MFMA(*(const short8*)&Pl[(mt * 16 + r) * 136 + kc * 32 + qd * 8],
                              *(const short8*)&Vs[(dn * 16 + r) * 136 + kc * 32 + qd * 8],
                              oacc[mt][dn]);
  }

  // epilogue: ctx[b*S+s][h*64+d] = O / l
#pragma unroll
  for (int mt = 0; mt < 2; mt++)
#pragma unroll
    for (int i = 0; i < 4; i++) {
      float inv = 1.0f / lrun[mt][i];
      int s = q0 + mt * 16 + qd * 4 + i;
      size_t base = ((size_t)(b * SS + s)) * DM + h * DHD;
#pragma unroll
      for (int dn = 0; dn < 4; dn++) ctx[base + dn * 16 + r] = f2bf(oacc[mt][dn][i] * inv);
    }
}

// ---------------- launcher ----------------

extern "C" void kernel_launch(void* const* d_in, const int* in_sizes, int n_in,
                              void* d_out, int out_size, void* d_ws, size_t ws_size,
                              hipStream_t stream) {
  const float* hs = (const float*)d_in[0];
  const float* Wq = (const float*)d_in[1];
  const float* bq = (const float*)d_in[2];
  const float* Wk = (const float*)d_in[3];
  const float* bk = (const float*)d_in[4];
  const float* Wv = (const float*)d_in[5];
  const float* bv = (const float*)d_in[6];
  const float* Wo = (const float*)d_in[7];
  const float* bo = (const float*)d_in[8];

  char* ws = (char*)d_ws;
  unsigned short* Xbf = (unsigned short*)(ws + 0);         // 12.58 MB; later reused as ctx
  unsigned short* WqT = (unsigned short*)(ws + 12582912);  // 1.18 MB each
  unsigned short* WkT = (unsigned short*)(ws + 13762560);
  unsigned short* WvT = (unsigned short*)(ws + 14942208);
  unsigned short* WoT = (unsigned short*)(ws + 16121856);
  unsigned short* Qb = (unsigned short*)(ws + 17301504);   // 12.58 MB
  unsigned short* Kb = (unsigned short*)(ws + 29884416);   // 12.58 MB
  unsigned short* Vt = (unsigned short*)(ws + 42467328);   // 12.58 MB (end ~55.05 MB)

  convert_x<<<2048, 256, 0, stream>>>(hs, Xbf, MTOK * DM / 4);
  dim3 tb(32, 8);
  wtrans<<<dim3(24, 24), tb, 0, stream>>>(Wq, WqT);
  wtrans<<<dim3(24, 24), tb, 0, stream>>>(Wk, WkT);
  wtrans<<<dim3(24, 24), tb, 0, stream>>>(Wv, WvT);
  wtrans<<<dim3(24, 24), tb, 0, stream>>>(Wo, WoT);

  gemm128<0><<<dim3(64, 6), 256, 0, stream>>>(Xbf, WqT, bq, Qb);
  gemm128<1><<<dim3(64, 6), 256, 0, stream>>>(Xbf, WkT, bk, Kb);
  gemm128<2><<<dim3(64, 6), 256, 0, stream>>>(Xbf, WvT, bv, Vt);

  attn<<<dim3(32, NH, NB), 256, 0, stream>>>(Qb, Kb, Vt, Xbf);

  gemm128<3><<<dim3(64, 6), 256, 0, stream>>>(Xbf, WoT, bo, d_out);
}

// Round 3
// 256.406 us; speedup vs baseline: 1.9690x; 1.9690x over previous
//
#include <hip/hip_runtime.h>
#include <hip/hip_bf16.h>
#include <stdint.h>

// Problem constants
#define NH 12
#define DHD 64
#define DM 768
#define NB 2
#define SS 4096
#define MTOK 8192  // NB*SS

typedef __attribute__((ext_vector_type(8))) short short8;
typedef __attribute__((ext_vector_type(4))) float f32x4;
typedef __attribute__((ext_vector_type(16))) float f32x16;
typedef __attribute__((ext_vector_type(4))) unsigned short ushort4v;
typedef __attribute__((ext_vector_type(4))) unsigned int uint4v;

#define MFMA16(a, b, c) __builtin_amdgcn_mfma_f32_16x16x32_bf16(a, b, c, 0, 0, 0)
#define MFMA32(a, b, c) __builtin_amdgcn_mfma_f32_32x32x16_bf16(a, b, c, 0, 0, 0)

// Q is pre-scaled by SCALE*log2(e) so softmax works in exp2 domain.
#define QSCALE 0.18033688f  // 0.125 * 1.4426950408889634

#define CVTPK(d, a, b) asm("v_cvt_pk_bf16_f32 %0, %1, %2" : "=v"(d) : "v"(a), "v"(b))
// v_permlane32_swap_b32 vdst, vsrc : vdst.hi-lanes <-> vsrc.lo-lanes
#define SWAP32(a, b) asm("v_permlane32_swap_b32 %0, %1" : "+v"(a), "+v"(b))

static __device__ __forceinline__ unsigned short f2bf(float f) {
  union { float f; unsigned int u; } c; c.f = f;
  unsigned int r = (c.u + 0x7FFFu + ((c.u >> 16) & 1u)) >> 16;
  return (unsigned short)r;
}

static __device__ __forceinline__ void gld_lds16(const void* g, void* l) {
  __builtin_amdgcn_global_load_lds(
      (const __attribute__((address_space(1))) unsigned int*)g,
      (__attribute__((address_space(3))) unsigned int*)l, 16, 0, 0);
}

// ---------------- conversion kernels ----------------

__global__ void convert_x(const float* __restrict__ x, unsigned short* __restrict__ xb, int n4) {
  int i = blockIdx.x * blockDim.x + threadIdx.x;
  int stride = gridDim.x * blockDim.x;
  for (; i < n4; i += stride) {
    float4 v = ((const float4*)x)[i];
    ushort4v o;
    o[0] = f2bf(v.x); o[1] = f2bf(v.y); o[2] = f2bf(v.z); o[3] = f2bf(v.w);
    ((ushort4v*)xb)[i] = o;
  }
}

// W[k][n] fp32 -> WT[n][k] bf16 (LDS-tiled transpose)
__global__ void wtrans(const float* __restrict__ W, unsigned short* __restrict__ WT) {
  __shared__ float t[32][33];
  int tx = threadIdx.x, ty = threadIdx.y;
  int bx = blockIdx.x * 32, by = blockIdx.y * 32;
#pragma unroll
  for (int k = 0; k < 4; k++) t[ty + 8 * k][tx] = W[(size_t)(by + ty + 8 * k) * DM + bx + tx];
  __syncthreads();
#pragma unroll
  for (int k = 0; k < 4; k++)
    WT[(size_t)(bx + ty + 8 * k) * DM + by + tx] = f2bf(t[tx][ty + 8 * k]);
}

// ---------------- GEMM: C[M=8192][N=768] = A[8192][768] @ BT[n][k]^T + bias ----------------
// MODE 0: Q out bf16 [(b*12+h)*4096+s][64], scaled by QSCALE
// MODE 1: K out bf16 same layout
// MODE 2: V out bf16 transposed [(b*12+h)*64+d][4096]
// MODE 3: fp32 out [m][768] (final output)

template <int MODE>
__global__ __launch_bounds__(256, 2) void gemm128(const unsigned short* __restrict__ A,
                                                  const unsigned short* __restrict__ BT,
                                                  const float* __restrict__ bias,
                                                  void* __restrict__ out) {
  __shared__ unsigned short As[128 * 32];
  __shared__ unsigned short Bs[128 * 32];
  const int tid = threadIdx.x;
  const int wave = tid >> 6, lane = tid & 63;
  const int qd = lane >> 4, r = lane & 15;
  const int bm = blockIdx.x, bn = blockIdx.y;
  const int wr = (wave >> 1) * 64, wc = (wave & 1) * 64;

  f32x4 acc[4][4] = {};

  for (int k0 = 0; k0 < DM; k0 += 32) {
    __syncthreads();
#pragma unroll
    for (int p = 0; p < 2; p++) {
      int g = (wave * 2 + p) * 64 + lane;
      int row = g >> 2, ko = (g & 3) << 3;
      gld_lds16(A + (size_t)(bm * 128 + row) * DM + k0 + ko, &As[(wave * 2 + p) * 512]);
      gld_lds16(BT + (size_t)(bn * 128 + row) * DM + k0 + ko, &Bs[(wave * 2 + p) * 512]);
    }
    __syncthreads();

    short8 af[4], bfr[4];
#pragma unroll
    for (int mi = 0; mi < 4; mi++) af[mi] = *(const short8*)&As[(wr + mi * 16 + r) * 32 + qd * 8];
#pragma unroll
    for (int ni = 0; ni < 4; ni++) bfr[ni] = *(const short8*)&Bs[(wc + ni * 16 + r) * 32 + qd * 8];
#pragma unroll
    for (int mi = 0; mi < 4; mi++)
#pragma unroll
      for (int ni = 0; ni < 4; ni++) acc[mi][ni] = MFMA16(af[mi], bfr[ni], acc[mi][ni]);
  }

#pragma unroll
  for (int ni = 0; ni < 4; ni++) {
    int n = bn * 128 + wc + ni * 16 + r;
    float bv = bias[n];
#pragma unroll
    for (int mi = 0; mi < 4; mi++) {
      int m0 = bm * 128 + wr + mi * 16 + qd * 4;
      f32x4 v = acc[mi][ni];
      if (MODE == 3) {
        float* O = (float*)out;
#pragma unroll
        for (int i = 0; i < 4; i++) O[(size_t)(m0 + i) * DM + n] = v[i] + bv;
      } else if (MODE == 2) {
        unsigned short* O = (unsigned short*)out;
        int h = n >> 6, d = n & 63;
        int b = m0 >> 12, s = m0 & 4095;
        ushort4v pk;
        pk[0] = f2bf(v[0] + bv); pk[1] = f2bf(v[1] + bv);
        pk[2] = f2bf(v[2] + bv); pk[3] = f2bf(v[3] + bv);
        *(ushort4v*)&O[((size_t)((b * NH + h) * DHD + d)) * SS + s] = pk;
      } else {
        unsigned short* O = (unsigned short*)out;
        int h = n >> 6, d = n & 63;
        const float sc = (MODE == 0) ? QSCALE : 1.0f;
#pragma unroll
        for (int i = 0; i < 4; i++) {
          int m = m0 + i, b = m >> 12, s = m & 4095;
          O[((size_t)((b * NH + h) * SS + s)) * DHD + d] = f2bf((v[i] + bv) * sc);
        }
      }
    }
  }
}

// ---------------- flash attention v2: 32x32 MFMA, swapped QK^T, in-register P ----------------
// Q,K: [(b*H+h)*S + s][64] bf16 (Q pre-scaled by QSCALE); VT: [(b*H+h)*64 + d][S] bf16
// ctx out: [b*S+s][768] bf16
// Per block: 4 waves x 32 q-rows = 128 q. KVBLK=64, double-buffered swizzled LDS (32 KB).
__global__ __launch_bounds__(256, 4) void attn2(const unsigned short* __restrict__ Q,
                                                const unsigned short* __restrict__ K,
                                                const unsigned short* __restrict__ VT,
                                                unsigned short* __restrict__ ctx) {
  // LDS: buf{0,1} x { K[64 rows][64 cols, 16B-swizzled], V^T[64 d][64 keys, swizzled] }
  __shared__ __align__(16) unsigned short sh[16384];  // 32768 B
  const int tid = threadIdx.x;
  const int w = tid >> 6, lane = tid & 63;
  const int ln = lane & 31, hi = lane >> 5;
  const int qt = blockIdx.x, h = blockIdx.y, b = blockIdx.z;
  const int bh = b * NH + h;
  const unsigned short* Qh = Q + (size_t)bh * SS * DHD;
  const unsigned short* Kh = K + (size_t)bh * SS * DHD;
  const unsigned short* Vh = VT + (size_t)bh * DHD * SS;
  const int q0 = qt * 128 + w * 32;

  // stage one KV tile (64 keys): K 8KB + V 8KB, XOR-swizzled via pre-swizzled global src
  auto stage = [&](int kv, int bsel) {
    unsigned short* Kb = sh + (bsel << 13);
    unsigned short* Vb = Kb + 4096;
#pragma unroll
    for (int p = 0; p < 2; p++) {
      int g = ((w << 1) + p) * 64 + lane;
      int row = g >> 3, c = g & 7;
      int cs = (c ^ (row & 7)) << 3;  // element offset of the 16B chunk, swizzled
      gld_lds16(Kh + (size_t)(kv + row) * DHD + cs, Kb + (((w << 1) + p) << 9));
      gld_lds16(Vh + (size_t)row * SS + kv + cs, Vb + (((w << 1) + p) << 9));
    }
  };

  // Q B-fragments (contraction = dh): lane holds Q[q=ln][dh = kc*16 + hi*8 + j]
  short8 qf[4];
#pragma unroll
  for (int kc = 0; kc < 4; kc++)
    qf[kc] = *(const short8*)&Qh[(size_t)(q0 + ln) * DHD + kc * 16 + hi * 8];
  // launder so the compiler doesn't tie in-loop waits to these loads
#pragma unroll
  for (int kc = 0; kc < 4; kc++) asm volatile("" : "+v"(qf[kc]));

  stage(0, 0);

  float mrun = -1e30f, lrun = 0.f;
  f32x16 o0 = {}, o1 = {};
  int buf = 0;

  for (int t = 0; t < SS / 64; t++) {
    if (t < SS / 64 - 1) {
      stage((t + 1) << 6, buf ^ 1);
      asm volatile("s_waitcnt vmcnt(4)" ::: "memory");  // current tile staged; next in flight
    } else {
      asm volatile("s_waitcnt vmcnt(0)" ::: "memory");
    }
    __builtin_amdgcn_s_barrier();

    const unsigned short* Kb = sh + (buf << 13);
    const unsigned short* Vb = Kb + 4096;

    // S^T[key][q] = K Q^T : s0 = keys 0-31, s1 = keys 32-63 (C: col=q=ln, row=key)
    f32x16 s0 = {}, s1 = {};
#pragma unroll
    for (int kc = 0; kc < 4; kc++) {
      int sl = (((kc << 1) + hi) ^ (ln & 7)) << 3;
      s0 = MFMA32(*(const short8*)&Kb[(ln << 6) + sl], qf[kc], s0);
      s1 = MFMA32(*(const short8*)&Kb[((32 + ln) << 6) + sl], qf[kc], s1);
    }

    // ---- online softmax (exp2 domain), per lane: one q-column, 32 keys ----
    float m8[8];
#pragma unroll
    for (int i = 0; i < 8; i++)
      m8[i] = fmaxf(fmaxf(s0[i], s0[i + 8]), fmaxf(s1[i], s1[i + 8]));
#pragma unroll
    for (int i = 0; i < 4; i++) m8[i] = fmaxf(m8[i], m8[i + 4]);
    float mx = fmaxf(fmaxf(m8[0], m8[1]), fmaxf(m8[2], m8[3]));
    mx = fmaxf(mx, __shfl_xor(mx, 32));
    float mn = fmaxf(mrun, mx);
    float scl = __builtin_amdgcn_exp2f(mrun - mn);
    mrun = mn;
#pragma unroll
    for (int i = 0; i < 16; i++) {
      s0[i] = __builtin_amdgcn_exp2f(s0[i] - mn);
      s1[i] = __builtin_amdgcn_exp2f(s1[i] - mn);
    }
    float a8[8];
#pragma unroll
    for (int i = 0; i < 8; i++) a8[i] = (s0[i] + s0[i + 8]) + (s1[i] + s1[i + 8]);
#pragma unroll
    for (int i = 0; i < 4; i++) a8[i] += a8[i + 4];
    float rs = (a8[0] + a8[1]) + (a8[2] + a8[3]);
    rs += __shfl_xor(rs, 32);
    lrun = lrun * scl + rs;
    o0 *= scl;
    o1 *= scl;

    // ---- P -> bf16 B-frags in-register (cvt_pk + permlane32_swap), then PV ----
    // s reg r holds key (r&3)+8*(r>>2)+4*hi. cvt_pk pairs:
    //   w0=(0,1)/(4,5)  w1=(2,3)/(6,7)  w2=(8,9)/(12,13)  w3=(10,11)/(14,15)   [hi=0/hi=1]
    //   w4=(16,17)/(20,21) w5=(18,19)/(22,23) w6=(24,25)/(28,29) w7=(26,27)/(30,31)
    // SWAP32(a,b): a.hi-lanes <-> b.lo-lanes. SWAP32(w0,w2) -> w0=[(0,1)|(8,9)] w2=[(4,5)|(12,13)]
#pragma unroll
    for (int kt = 0; kt < 2; kt++) {
      f32x16& sv = kt ? s1 : s0;
      unsigned int w0, w1, w2, w3, w4, w5, w6, w7;
      CVTPK(w0, sv[0], sv[1]);   CVTPK(w1, sv[2], sv[3]);
      CVTPK(w2, sv[4], sv[5]);   CVTPK(w3, sv[6], sv[7]);
      CVTPK(w4, sv[8], sv[9]);   CVTPK(w5, sv[10], sv[11]);
      CVTPK(w6, sv[12], sv[13]); CVTPK(w7, sv[14], sv[15]);
      SWAP32(w0, w2);
      SWAP32(w1, w3);
      SWAP32(w4, w6);
      SWAP32(w5, w7);
      union { uint4v u; short8 s; } b0, b1;
      b0.u = (uint4v){w0, w1, w2, w3};  // B-frag k = kt*32 + [0,16)
      b1.u = (uint4v){w4, w5, w6, w7};  // B-frag k = kt*32 + [16,32)
      int sl0 = (((kt << 2) + hi) ^ (ln & 7)) << 3;      // c16 = kt*4 + 0 + hi
      int sl1 = (((kt << 2) + 2 + hi) ^ (ln & 7)) << 3;  // c16 = kt*4 + 2 + hi
      o0 = MFMA32(*(const short8*)&Vb[(ln << 6) + sl0], b0.s, o0);
      o1 = MFMA32(*(const short8*)&Vb[((32 + ln) << 6) + sl0], b0.s, o1);
      o0 = MFMA32(*(const short8*)&Vb[(ln << 6) + sl1], b1.s, o0);
      o1 = MFMA32(*(const short8*)&Vb[((32 + ln) << 6) + sl1], b1.s, o1);
    }

    __builtin_amdgcn_s_barrier();  // all reads of buf done before next stage overwrites it
    buf ^= 1;
  }

  // epilogue: O^T[d][q] -> ctx[b*S+sq][h*64+d], lane q = ln, d = dn*32 + q2*8 + hi*4 + i
  float inv = 1.0f / lrun;
  int sq = q0 + ln;
  unsigned short* cp = ctx + ((size_t)(b * SS + sq)) * DM + h * DHD;
#pragma unroll
  for (int q2 = 0; q2 < 4; q2++) {
    unsigned int pl, ph;
    CVTPK(pl, o0[q2 * 4 + 0] * inv, o0[q2 * 4 + 1] * inv);
    CVTPK(ph, o0[q2 * 4 + 2] * inv, o0[q2 * 4 + 3] * inv);
    uint2 st0; st0.x = pl; st0.y = ph;
    *(uint2*)(cp + q2 * 8 + hi * 4) = st0;
    CVTPK(pl, o1[q2 * 4 + 0] * inv, o1[q2 * 4 + 1] * inv);
    CVTPK(ph, o1[q2 * 4 + 2] * inv, o1[q2 * 4 + 3] * inv);
    uint2 st1; st1.x = pl; st1.y = ph;
    *(uint2*)(cp + 32 + q2 * 8 + hi * 4) = st1;
  }
}

// ---------------- launcher ----------------

extern "C" void kernel_launch(void* const* d_in, const int* in_sizes, int n_in,
                              void* d_out, int out_size, void* d_ws, size_t ws_size,
                              hipStream_t stream) {
  const float* hs = (const float*)d_in[0];
  const float* Wq = (const float*)d_in[1];
  const float* bq = (const float*)d_in[2];
  const float* Wk = (const float*)d_in[3];
  const float* bk = (const float*)d_in[4];
  const float* Wv = (const float*)d_in[5];
  const float* bv = (const float*)d_in[6];
  const float* Wo = (const float*)d_in[7];
  const float* bo = (const float*)d_in[8];

  char* ws = (char*)d_ws;
  unsigned short* Xbf = (unsigned short*)(ws + 0);         // 12.58 MB; later reused as ctx
  unsigned short* WqT = (unsigned short*)(ws + 12582912);  // 1.18 MB each
  unsigned short* WkT = (unsigned short*)(ws + 13762560);
  unsigned short* WvT = (unsigned short*)(ws + 14942208);
  unsigned short* WoT = (unsigned short*)(ws + 16121856);
  unsigned short* Qb = (unsigned short*)(ws + 17301504);   // 12.58 MB
  unsigned short* Kb = (unsigned short*)(ws + 29884416);   // 12.58 MB
  unsigned short* Vt = (unsigned short*)(ws + 42467328);   // 12.58 MB (end ~55.05 MB)

  convert_x<<<2048, 256, 0, stream>>>(hs, Xbf, MTOK * DM / 4);
  dim3 tb(32, 8);
  wtrans<<<dim3(24, 24), tb, 0, stream>>>(Wq, WqT);
  wtrans<<<dim3(24, 24), tb, 0, stream>>>(Wk, WkT);
  wtrans<<<dim3(24, 24), tb, 0, stream>>>(Wv, WvT);
  wtrans<<<dim3(24, 24), tb, 0, stream>>>(Wo, WoT);

  gemm128<0><<<dim3(64, 6), 256, 0, stream>>>(Xbf, WqT, bq, Qb);
  gemm128<1><<<dim3(64, 6), 256, 0, stream>>>(Xbf, WkT, bk, Kb);
  gemm128<2><<<dim3(64, 6), 256, 0, stream>>>(Xbf, WvT, bv, Vt);

  attn2<<<dim3(32, NH, NB), 256, 0, stream>>>(Qb, Kb, Vt, Xbf);

  gemm128<3><<<dim3(64, 6), 256, 0, stream>>>(Xbf, WoT, bo, d_out);
}

// Round 4
// 235.202 us; speedup vs baseline: 2.1465x; 1.0902x over previous
//
#include <hip/hip_runtime.h>
#include <hip/hip_bf16.h>
#include <stdint.h>

// Problem constants
#define NH 12
#define DHD 64
#define DM 768
#define NB 2
#define SS 4096
#define MTOK 8192  // NB*SS

typedef __attribute__((ext_vector_type(8))) short short8;
typedef __attribute__((ext_vector_type(4))) float f32x4;
typedef __attribute__((ext_vector_type(16))) float f32x16;
typedef __attribute__((ext_vector_type(4))) unsigned short ushort4v;
typedef __attribute__((ext_vector_type(4))) unsigned int uint4v;

#define MFMA16(a, b, c) __builtin_amdgcn_mfma_f32_16x16x32_bf16(a, b, c, 0, 0, 0)
#define MFMA32(a, b, c) __builtin_amdgcn_mfma_f32_32x32x16_bf16(a, b, c, 0, 0, 0)

// Q is pre-scaled by SCALE*log2(e) so softmax works in exp2 domain.
#define QSCALE 0.18033688f  // 0.125 * 1.4426950408889634

#define CVTPK(d, a, b) asm("v_cvt_pk_bf16_f32 %0, %1, %2" : "=v"(d) : "v"(a), "v"(b))
// v_permlane32_swap_b32 vdst, vsrc : vdst.hi-lanes <-> vsrc.lo-lanes
#define SWAP32(a, b) asm("v_permlane32_swap_b32 %0, %1" : "+v"(a), "+v"(b))

static __device__ __forceinline__ unsigned short f2bf(float f) {
  union { float f; unsigned int u; } c; c.f = f;
  unsigned int r = (c.u + 0x7FFFu + ((c.u >> 16) & 1u)) >> 16;
  return (unsigned short)r;
}

static __device__ __forceinline__ void gld_lds16(const void* g, void* l) {
  __builtin_amdgcn_global_load_lds(
      (const __attribute__((address_space(1))) unsigned int*)g,
      (__attribute__((address_space(3))) unsigned int*)l, 16, 0, 0);
}

// ---------------- conversion kernels ----------------

__global__ void convert_x(const float* __restrict__ x, unsigned short* __restrict__ xb, int n4) {
  int i = blockIdx.x * blockDim.x + threadIdx.x;
  int stride = gridDim.x * blockDim.x;
  for (; i < n4; i += stride) {
    float4 v = ((const float4*)x)[i];
    ushort4v o;
    o[0] = f2bf(v.x); o[1] = f2bf(v.y); o[2] = f2bf(v.z); o[3] = f2bf(v.w);
    ((ushort4v*)xb)[i] = o;
  }
}

// W[k][n] fp32 -> WT[n][k] bf16 (LDS-tiled transpose)
__global__ void wtrans(const float* __restrict__ W, unsigned short* __restrict__ WT) {
  __shared__ float t[32][33];
  int tx = threadIdx.x, ty = threadIdx.y;
  int bx = blockIdx.x * 32, by = blockIdx.y * 32;
#pragma unroll
  for (int k = 0; k < 4; k++) t[ty + 8 * k][tx] = W[(size_t)(by + ty + 8 * k) * DM + bx + tx];
  __syncthreads();
#pragma unroll
  for (int k = 0; k < 4; k++)
    WT[(size_t)(bx + ty + 8 * k) * DM + by + tx] = f2bf(t[tx][ty + 8 * k]);
}

// ---------------- fused QKV GEMM ----------------
// C[8192][2304] = X[8192][768] @ WqkvT^T + bias, epilogue routed by bn:
//   bn 0-5  -> Q bf16 [(b*12+h)*4096+s][64] scaled by QSCALE
//   bn 6-11 -> K bf16 same layout
//   bn 12-17-> V bf16 transposed [(b*12+h)*64+d][4096]
__global__ __launch_bounds__(256, 2) void gemm_qkv(const unsigned short* __restrict__ A,
                                                   const unsigned short* __restrict__ WT,
                                                   const float* __restrict__ bq,
                                                   const float* __restrict__ bk,
                                                   const float* __restrict__ bv,
                                                   unsigned short* __restrict__ Qo,
                                                   unsigned short* __restrict__ Ko,
                                                   unsigned short* __restrict__ Vo) {
  __shared__ unsigned short As[128 * 32];
  __shared__ unsigned short Bs[128 * 32];
  const int tid = threadIdx.x;
  const int wave = tid >> 6, lane = tid & 63;
  const int qd = lane >> 4, r = lane & 15;
  const int bm = blockIdx.x, bn = blockIdx.y;
  const int wr = (wave >> 1) * 64, wc = (wave & 1) * 64;

  f32x4 acc[4][4] = {};

  for (int k0 = 0; k0 < DM; k0 += 32) {
    __syncthreads();
#pragma unroll
    for (int p = 0; p < 2; p++) {
      int g = (wave * 2 + p) * 64 + lane;
      int row = g >> 2, ko = (g & 3) << 3;
      gld_lds16(A + (size_t)(bm * 128 + row) * DM + k0 + ko, &As[(wave * 2 + p) * 512]);
      gld_lds16(WT + (size_t)(bn * 128 + row) * DM + k0 + ko, &Bs[(wave * 2 + p) * 512]);
    }
    __syncthreads();

    short8 af[4], bfr[4];
#pragma unroll
    for (int mi = 0; mi < 4; mi++) af[mi] = *(const short8*)&As[(wr + mi * 16 + r) * 32 + qd * 8];
#pragma unroll
    for (int ni = 0; ni < 4; ni++) bfr[ni] = *(const short8*)&Bs[(wc + ni * 16 + r) * 32 + qd * 8];
#pragma unroll
    for (int mi = 0; mi < 4; mi++)
#pragma unroll
      for (int ni = 0; ni < 4; ni++) acc[mi][ni] = MFMA16(af[mi], bfr[ni], acc[mi][ni]);
  }

  const int seg = bn / 6;  // 0=Q 1=K 2=V
  const float* bias = (seg == 0) ? bq : (seg == 1) ? bk : bv;
  unsigned short* O = (seg == 0) ? Qo : (seg == 1) ? Ko : Vo;
  const float sc = (seg == 0) ? QSCALE : 1.0f;

#pragma unroll
  for (int ni = 0; ni < 4; ni++) {
    int nl = (bn - seg * 6) * 128 + wc + ni * 16 + r;  // 0..767 within segment
    float bvv = bias[nl];
    int h = nl >> 6, d = nl & 63;
#pragma unroll
    for (int mi = 0; mi < 4; mi++) {
      int m0 = bm * 128 + wr + mi * 16 + qd * 4;
      int b = m0 >> 12, s0m = m0 & 4095;
      f32x4 v = acc[mi][ni];
      if (seg == 2) {
        ushort4v pk;
        pk[0] = f2bf(v[0] + bvv); pk[1] = f2bf(v[1] + bvv);
        pk[2] = f2bf(v[2] + bvv); pk[3] = f2bf(v[3] + bvv);
        *(ushort4v*)&O[((size_t)((b * NH + h) * DHD + d)) * SS + s0m] = pk;
      } else {
#pragma unroll
        for (int i = 0; i < 4; i++)
          O[((size_t)((b * NH + h) * SS + s0m + i)) * DHD + d] = f2bf((v[i] + bvv) * sc);
      }
    }
  }
}

// ---------------- output projection GEMM (fp32 out) ----------------
__global__ __launch_bounds__(256, 2) void gemm_out(const unsigned short* __restrict__ A,
                                                   const unsigned short* __restrict__ BT,
                                                   const float* __restrict__ bias,
                                                   float* __restrict__ out) {
  __shared__ unsigned short As[128 * 32];
  __shared__ unsigned short Bs[128 * 32];
  const int tid = threadIdx.x;
  const int wave = tid >> 6, lane = tid & 63;
  const int qd = lane >> 4, r = lane & 15;
  const int bm = blockIdx.x, bn = blockIdx.y;
  const int wr = (wave >> 1) * 64, wc = (wave & 1) * 64;

  f32x4 acc[4][4] = {};

  for (int k0 = 0; k0 < DM; k0 += 32) {
    __syncthreads();
#pragma unroll
    for (int p = 0; p < 2; p++) {
      int g = (wave * 2 + p) * 64 + lane;
      int row = g >> 2, ko = (g & 3) << 3;
      gld_lds16(A + (size_t)(bm * 128 + row) * DM + k0 + ko, &As[(wave * 2 + p) * 512]);
      gld_lds16(BT + (size_t)(bn * 128 + row) * DM + k0 + ko, &Bs[(wave * 2 + p) * 512]);
    }
    __syncthreads();

    short8 af[4], bfr[4];
#pragma unroll
    for (int mi = 0; mi < 4; mi++) af[mi] = *(const short8*)&As[(wr + mi * 16 + r) * 32 + qd * 8];
#pragma unroll
    for (int ni = 0; ni < 4; ni++) bfr[ni] = *(const short8*)&Bs[(wc + ni * 16 + r) * 32 + qd * 8];
#pragma unroll
    for (int mi = 0; mi < 4; mi++)
#pragma unroll
      for (int ni = 0; ni < 4; ni++) acc[mi][ni] = MFMA16(af[mi], bfr[ni], acc[mi][ni]);
  }

#pragma unroll
  for (int ni = 0; ni < 4; ni++) {
    int n = bn * 128 + wc + ni * 16 + r;
    float bvv = bias[n];
#pragma unroll
    for (int mi = 0; mi < 4; mi++) {
      int m0 = bm * 128 + wr + mi * 16 + qd * 4;
      f32x4 v = acc[mi][ni];
#pragma unroll
      for (int i = 0; i < 4; i++) out[(size_t)(m0 + i) * DM + n] = v[i] + bvv;
    }
  }
}

// ---------------- flash attention v3: deferred-PV pipeline, ring-3 LDS ----------------
// Q,K: [(b*H+h)*S + s][64] bf16 (Q pre-scaled by QSCALE); VT: [(b*H+h)*64 + d][S] bf16
// ctx out: [b*S+s][768] bf16
// 4 waves x 32 q. KVBLK=64. Ring-3 swizzled LDS bufs (48 KB), 1 barrier/tile.
// Iter t: QK^T(t) || [o*=scl(t-1); PV(t-1)] -> softmax(t) -> P-frags(t).
__global__ __launch_bounds__(256, 3) void attn3(const unsigned short* __restrict__ Q,
                                                const unsigned short* __restrict__ K,
                                                const unsigned short* __restrict__ VT,
                                                unsigned short* __restrict__ ctx) {
  __shared__ __align__(16) unsigned short sh[24576];  // 3 bufs x (K 4096 + V 4096) = 49152 B
  const int tid = threadIdx.x;
  const int w = tid >> 6, lane = tid & 63;
  const int ln = lane & 31, hi = lane >> 5;
  const int qt = blockIdx.x, h = blockIdx.y, b = blockIdx.z;
  const int bh = b * NH + h;
  const unsigned short* Qh = Q + (size_t)bh * SS * DHD;
  const unsigned short* Kh = K + (size_t)bh * SS * DHD;
  const unsigned short* Vh = VT + (size_t)bh * DHD * SS;
  const int q0 = qt * 128 + w * 32;

  // stage tile (64 keys): K 8KB + V 8KB, XOR-swizzled via pre-swizzled global src
  auto stage = [&](int kv, unsigned short* base) {
#pragma unroll
    for (int p = 0; p < 2; p++) {
      int g = ((w << 1) + p) * 64 + lane;
      int row = g >> 3, c = g & 7;
      int cs = (c ^ (row & 7)) << 3;
      gld_lds16(Kh + (size_t)(kv + row) * DHD + cs, base + (((w << 1) + p) << 9));
      gld_lds16(Vh + (size_t)row * SS + kv + cs, base + 4096 + (((w << 1) + p) << 9));
    }
  };

  // Q B-fragments: lane holds Q[q=ln][dh = kc*16 + hi*8 + j]
  short8 qf[4];
#pragma unroll
  for (int kc = 0; kc < 4; kc++)
    qf[kc] = *(const short8*)&Qh[(size_t)(q0 + ln) * DHD + kc * 16 + hi * 8];
#pragma unroll
  for (int kc = 0; kc < 4; kc++) asm volatile("" : "+v"(qf[kc]));

  unsigned short* bprev = sh + 16384;
  unsigned short* bcur = sh;
  unsigned short* bnxt = sh + 8192;

  stage(0, bcur);

  float mrun = -1e30f, lrun = 0.f, sclp = 0.f;
  f32x16 o0 = {}, o1 = {};
  f32x16 s0, s1;
  union PF { uint4v u; short8 s; };
  PF pf0, pf1, pf2, pf3;

  // QK^T into s0,s1 from K buffer
  auto qk = [&](const unsigned short* Kb) {
#pragma unroll
    for (int i = 0; i < 16; i++) { s0[i] = 0.f; s1[i] = 0.f; }
    __builtin_amdgcn_s_setprio(1);
#pragma unroll
    for (int kc = 0; kc < 4; kc++) {
      int sl = (((kc << 1) + hi) ^ (ln & 7)) << 3;
      s0 = MFMA32(*(const short8*)&Kb[(ln << 6) + sl], qf[kc], s0);
      s1 = MFMA32(*(const short8*)&Kb[((32 + ln) << 6) + sl], qf[kc], s1);
    }
    __builtin_amdgcn_s_setprio(0);
  };

  // rescale o by sclp and accumulate PV of the PREVIOUS tile (pf*, V in Vb)
  auto pv = [&](const unsigned short* Vb) {
    o0 *= sclp;
    o1 *= sclp;
    __builtin_amdgcn_s_setprio(1);
    {
      int sl0 = ((0 + hi) ^ (ln & 7)) << 3;
      int sl1 = ((2 + hi) ^ (ln & 7)) << 3;
      o0 = MFMA32(*(const short8*)&Vb[(ln << 6) + sl0], pf0.s, o0);
      o1 = MFMA32(*(const short8*)&Vb[((32 + ln) << 6) + sl0], pf0.s, o1);
      o0 = MFMA32(*(const short8*)&Vb[(ln << 6) + sl1], pf1.s, o0);
      o1 = MFMA32(*(const short8*)&Vb[((32 + ln) << 6) + sl1], pf1.s, o1);
    }
    {
      int sl0 = ((4 + hi) ^ (ln & 7)) << 3;
      int sl1 = ((6 + hi) ^ (ln & 7)) << 3;
      o0 = MFMA32(*(const short8*)&Vb[(ln << 6) + sl0], pf2.s, o0);
      o1 = MFMA32(*(const short8*)&Vb[((32 + ln) << 6) + sl0], pf2.s, o1);
      o0 = MFMA32(*(const short8*)&Vb[(ln << 6) + sl1], pf3.s, o0);
      o1 = MFMA32(*(const short8*)&Vb[((32 + ln) << 6) + sl1], pf3.s, o1);
    }
    __builtin_amdgcn_s_setprio(0);
  };

  // softmax on s0,s1 -> new pf*, sclp, mrun, lrun
  auto sm = [&]() {
    float m8[8];
#pragma unroll
    for (int i = 0; i < 8; i++)
      m8[i] = fmaxf(fmaxf(s0[i], s0[i + 8]), fmaxf(s1[i], s1[i + 8]));
#pragma unroll
    for (int i = 0; i < 4; i++) m8[i] = fmaxf(m8[i], m8[i + 4]);
    float mx = fmaxf(fmaxf(m8[0], m8[1]), fmaxf(m8[2], m8[3]));
    mx = fmaxf(mx, __shfl_xor(mx, 32));
    float mn = fmaxf(mrun, mx);
    sclp = __builtin_amdgcn_exp2f(mrun - mn);
    mrun = mn;
#pragma unroll
    for (int i = 0; i < 16; i++) {
      s0[i] = __builtin_amdgcn_exp2f(s0[i] - mn);
      s1[i] = __builtin_amdgcn_exp2f(s1[i] - mn);
    }
    float a8[8];
#pragma unroll
    for (int i = 0; i < 8; i++) a8[i] = (s0[i] + s0[i + 8]) + (s1[i] + s1[i + 8]);
#pragma unroll
    for (int i = 0; i < 4; i++) a8[i] += a8[i + 4];
    float rs = (a8[0] + a8[1]) + (a8[2] + a8[3]);
    rs += __shfl_xor(rs, 32);
    lrun = lrun * sclp + rs;
    // P -> bf16 B-frags (cvt_pk + permlane32_swap). s reg r holds key (r&3)+8*(r>>2)+4*hi.
    {
      unsigned int w0, w1, w2, w3, w4, w5, w6, w7;
      CVTPK(w0, s0[0], s0[1]);   CVTPK(w1, s0[2], s0[3]);
      CVTPK(w2, s0[4], s0[5]);   CVTPK(w3, s0[6], s0[7]);
      CVTPK(w4, s0[8], s0[9]);   CVTPK(w5, s0[10], s0[11]);
      CVTPK(w6, s0[12], s0[13]); CVTPK(w7, s0[14], s0[15]);
      SWAP32(w0, w2); SWAP32(w1, w3); SWAP32(w4, w6); SWAP32(w5, w7);
      pf0.u = (uint4v){w0, w1, w2, w3};
      pf1.u = (uint4v){w4, w5, w6, w7};
    }
    {
      unsigned int w0, w1, w2, w3, w4, w5, w6, w7;
      CVTPK(w0, s1[0], s1[1]);   CVTPK(w1, s1[2], s1[3]);
      CVTPK(w2, s1[4], s1[5]);   CVTPK(w3, s1[6], s1[7]);
      CVTPK(w4, s1[8], s1[9]);   CVTPK(w5, s1[10], s1[11]);
      CVTPK(w6, s1[12], s1[13]); CVTPK(w7, s1[14], s1[15]);
      SWAP32(w0, w2); SWAP32(w1, w3); SWAP32(w4, w6); SWAP32(w5, w7);
      pf2.u = (uint4v){w0, w1, w2, w3};
      pf3.u = (uint4v){w4, w5, w6, w7};
    }
  };

  // ---- peeled iteration 0 ----
  asm volatile("s_waitcnt vmcnt(0)" ::: "memory");
  __builtin_amdgcn_s_barrier();
  stage(64, bnxt);
  qk(bcur);
  sm();
  { unsigned short* t = bprev; bprev = bcur; bcur = bnxt; bnxt = t; }

  // ---- main loop t = 1..63 ----
  for (int t = 1; t < SS / 64; t++) {
    asm volatile("s_waitcnt vmcnt(0)" ::: "memory");
    __builtin_amdgcn_s_barrier();
    if (t < SS / 64 - 1) stage((t + 1) << 6, bnxt);
    qk(bcur);
    pv(bprev + 4096);
    sm();
    { unsigned short* tp = bprev; bprev = bcur; bcur = bnxt; bnxt = tp; }
  }

  // tail: PV of last tile (its V is in bprev after final rotation)
  pv(bprev + 4096);

  // epilogue: O^T[d][q] -> ctx[b*S+sq][h*64+d]
  float inv = 1.0f / lrun;
  int sq = q0 + ln;
  unsigned short* cp = ctx + ((size_t)(b * SS + sq)) * DM + h * DHD;
#pragma unroll
  for (int q2 = 0; q2 < 4; q2++) {
    unsigned int pl, ph;
    CVTPK(pl, o0[q2 * 4 + 0] * inv, o0[q2 * 4 + 1] * inv);
    CVTPK(ph, o0[q2 * 4 + 2] * inv, o0[q2 * 4 + 3] * inv);
    uint2 st0; st0.x = pl; st0.y = ph;
    *(uint2*)(cp + q2 * 8 + hi * 4) = st0;
    CVTPK(pl, o1[q2 * 4 + 0] * inv, o1[q2 * 4 + 1] * inv);
    CVTPK(ph, o1[q2 * 4 + 2] * inv, o1[q2 * 4 + 3] * inv);
    uint2 st1; st1.x = pl; st1.y = ph;
    *(uint2*)(cp + 32 + q2 * 8 + hi * 4) = st1;
  }
}

// ---------------- launcher ----------------

extern "C" void kernel_launch(void* const* d_in, const int* in_sizes, int n_in,
                              void* d_out, int out_size, void* d_ws, size_t ws_size,
                              hipStream_t stream) {
  const float* hs = (const float*)d_in[0];
  const float* Wq = (const float*)d_in[1];
  const float* bq = (const float*)d_in[2];
  const float* Wk = (const float*)d_in[3];
  const float* bk = (const float*)d_in[4];
  const float* Wv = (const float*)d_in[5];
  const float* bv = (const float*)d_in[6];
  const float* Wo = (const float*)d_in[7];
  const float* bo = (const float*)d_in[8];

  char* ws = (char*)d_ws;
  unsigned short* Xbf = (unsigned short*)(ws + 0);           // 12.58 MB; later reused as ctx
  unsigned short* WqkvT = (unsigned short*)(ws + 12582912);  // 2304x768 bf16 = 3.54 MB
  unsigned short* WoT = (unsigned short*)(ws + 16121856);    // 1.18 MB
  unsigned short* Qb = (unsigned short*)(ws + 17301504);     // 12.58 MB
  unsigned short* Kb = (unsigned short*)(ws + 29884416);     // 12.58 MB
  unsigned short* Vt = (unsigned short*)(ws + 42467328);     // 12.58 MB (end ~55.05 MB)

  convert_x<<<2048, 256, 0, stream>>>(hs, Xbf, MTOK * DM / 4);
  dim3 tb(32, 8);
  wtrans<<<dim3(24, 24), tb, 0, stream>>>(Wq, WqkvT);
  wtrans<<<dim3(24, 24), tb, 0, stream>>>(Wk, WqkvT + 589824);
  wtrans<<<dim3(24, 24), tb, 0, stream>>>(Wv, WqkvT + 1179648);
  wtrans<<<dim3(24, 24), tb, 0, stream>>>(Wo, WoT);

  gemm_qkv<<<dim3(64, 18), 256, 0, stream>>>(Xbf, WqkvT, bq, bk, bv, Qb, Kb, Vt);

  attn3<<<dim3(32, NH, NB), 256, 0, stream>>>(Qb, Kb, Vt, Xbf);

  gemm_out<<<dim3(64, 6), 256, 0, stream>>>(Xbf, WoT, bo, (float*)d_out);
}

// Round 8
// 224.016 us; speedup vs baseline: 2.2536x; 1.0499x over previous
//
#include <hip/hip_runtime.h>
#include <hip/hip_bf16.h>
#include <stdint.h>

// Problem constants
#define NH 12
#define DHD 64
#define DM 768
#define NB 2
#define SS 4096
#define MTOK 8192  // NB*SS

typedef __attribute__((ext_vector_type(8))) short short8;
typedef __attribute__((ext_vector_type(4))) float f32x4;
typedef __attribute__((ext_vector_type(16))) float f32x16;
typedef __attribute__((ext_vector_type(4))) unsigned short ushort4v;
typedef __attribute__((ext_vector_type(4))) unsigned int uint4v;

#define MFMA16(a, b, c) __builtin_amdgcn_mfma_f32_16x16x32_bf16(a, b, c, 0, 0, 0)
#define MFMA32(a, b, c) __builtin_amdgcn_mfma_f32_32x32x16_bf16(a, b, c, 0, 0, 0)

// Q is pre-scaled by SCALE*log2(e) so softmax works in exp2 domain.
#define QSCALE 0.18033688f  // 0.125 * 1.4426950408889634

#define CVTPK(d, a, b) asm("v_cvt_pk_bf16_f32 %0, %1, %2" : "=v"(d) : "v"(a), "v"(b))
// v_permlane32_swap_b32 vdst, vsrc : vdst.hi-lanes <-> vsrc.lo-lanes
#define SWAP32(a, b) asm("v_permlane32_swap_b32 %0, %1" : "+v"(a), "+v"(b))

static __device__ __forceinline__ unsigned short f2bf(float f) {
  union { float f; unsigned int u; } c; c.f = f;
  unsigned int r = (c.u + 0x7FFFu + ((c.u >> 16) & 1u)) >> 16;
  return (unsigned short)r;
}

static __device__ __forceinline__ void gld_lds16(const void* g, void* l) {
  __builtin_amdgcn_global_load_lds(
      (const __attribute__((address_space(1))) unsigned int*)g,
      (__attribute__((address_space(3))) unsigned int*)l, 16, 0, 0);
}

// ---------------- conversion kernels ----------------

__global__ void convert_x(const float* __restrict__ x, unsigned short* __restrict__ xb, int n4) {
  int i = blockIdx.x * blockDim.x + threadIdx.x;
  int stride = gridDim.x * blockDim.x;
  for (; i < n4; i += stride) {
    float4 v = ((const float4*)x)[i];
    ushort4v o;
    o[0] = f2bf(v.x); o[1] = f2bf(v.y); o[2] = f2bf(v.z); o[3] = f2bf(v.w);
    ((ushort4v*)xb)[i] = o;
  }
}

// All 4 weight transposes in one launch: W[k][n] fp32 -> WT[n][k] bf16.
// blockIdx.z selects the source weight; dst = WqkvT + z*589824 (WoT is contiguous after V).
__global__ void wtrans4(const float* __restrict__ Wq, const float* __restrict__ Wk,
                        const float* __restrict__ Wv, const float* __restrict__ Wo,
                        unsigned short* __restrict__ WT) {
  __shared__ float t[32][33];
  const int z = blockIdx.z;
  const float* W = (z == 0) ? Wq : (z == 1) ? Wk : (z == 2) ? Wv : Wo;
  unsigned short* dst = WT + (size_t)z * 589824;
  int tx = threadIdx.x, ty = threadIdx.y;
  int bx = blockIdx.x * 32, by = blockIdx.y * 32;
#pragma unroll
  for (int k = 0; k < 4; k++) t[ty + 8 * k][tx] = W[(size_t)(by + ty + 8 * k) * DM + bx + tx];
  __syncthreads();
#pragma unroll
  for (int k = 0; k < 4; k++)
    dst[(size_t)(bx + ty + 8 * k) * DM + by + tx] = f2bf(t[tx][ty + 8 * k]);
}

// ---------------- fused QKV GEMM ----------------
// C[8192][2304] = X[8192][768] @ WqkvT^T + bias, epilogue routed by bn:
//   bn 0-5  -> Q bf16 [(b*12+h)*4096+s][64] scaled by QSCALE
//   bn 6-11 -> K bf16 same layout
//   bn 12-17-> V bf16 transposed [(b*12+h)*64+d][4096]
__global__ __launch_bounds__(256, 2) void gemm_qkv(const unsigned short* __restrict__ A,
                                                   const unsigned short* __restrict__ WT,
                                                   const float* __restrict__ bq,
                                                   const float* __restrict__ bk,
                                                   const float* __restrict__ bv,
                                                   unsigned short* __restrict__ Qo,
                                                   unsigned short* __restrict__ Ko,
                                                   unsigned short* __restrict__ Vo) {
  __shared__ unsigned short As[128 * 32];
  __shared__ unsigned short Bs[128 * 32];
  const int tid = threadIdx.x;
  const int wave = tid >> 6, lane = tid & 63;
  const int qd = lane >> 4, r = lane & 15;
  const int bm = blockIdx.x, bn = blockIdx.y;
  const int wr = (wave >> 1) * 64, wc = (wave & 1) * 64;

  f32x4 acc[4][4] = {};

  for (int k0 = 0; k0 < DM; k0 += 32) {
    __syncthreads();
#pragma unroll
    for (int p = 0; p < 2; p++) {
      int g = (wave * 2 + p) * 64 + lane;
      int row = g >> 2, ko = (g & 3) << 3;
      gld_lds16(A + (size_t)(bm * 128 + row) * DM + k0 + ko, &As[(wave * 2 + p) * 512]);
      gld_lds16(WT + (size_t)(bn * 128 + row) * DM + k0 + ko, &Bs[(wave * 2 + p) * 512]);
    }
    __syncthreads();

    short8 af[4], bfr[4];
#pragma unroll
    for (int mi = 0; mi < 4; mi++) af[mi] = *(const short8*)&As[(wr + mi * 16 + r) * 32 + qd * 8];
#pragma unroll
    for (int ni = 0; ni < 4; ni++) bfr[ni] = *(const short8*)&Bs[(wc + ni * 16 + r) * 32 + qd * 8];
#pragma unroll
    for (int mi = 0; mi < 4; mi++)
#pragma unroll
      for (int ni = 0; ni < 4; ni++) acc[mi][ni] = MFMA16(af[mi], bfr[ni], acc[mi][ni]);
  }

  const int seg = bn / 6;  // 0=Q 1=K 2=V
  const float* bias = (seg == 0) ? bq : (seg == 1) ? bk : bv;
  unsigned short* O = (seg == 0) ? Qo : (seg == 1) ? Ko : Vo;
  const float sc = (seg == 0) ? QSCALE : 1.0f;

#pragma unroll
  for (int ni = 0; ni < 4; ni++) {
    int nl = (bn - seg * 6) * 128 + wc + ni * 16 + r;  // 0..767 within segment
    float bvv = bias[nl];
    int h = nl >> 6, d = nl & 63;
#pragma unroll
    for (int mi = 0; mi < 4; mi++) {
      int m0 = bm * 128 + wr + mi * 16 + qd * 4;
      int b = m0 >> 12, s0m = m0 & 4095;
      f32x4 v = acc[mi][ni];
      if (seg == 2) {
        ushort4v pk;
        pk[0] = f2bf(v[0] + bvv); pk[1] = f2bf(v[1] + bvv);
        pk[2] = f2bf(v[2] + bvv); pk[3] = f2bf(v[3] + bvv);
        *(ushort4v*)&O[((size_t)((b * NH + h) * DHD + d)) * SS + s0m] = pk;
      } else {
#pragma unroll
        for (int i = 0; i < 4; i++)
          O[((size_t)((b * NH + h) * SS + s0m + i)) * DHD + d] = f2bf((v[i] + bvv) * sc);
      }
    }
  }
}

// ---------------- output projection GEMM (fp32 out) ----------------
__global__ __launch_bounds__(256, 2) void gemm_out(const unsigned short* __restrict__ A,
                                                   const unsigned short* __restrict__ BT,
                                                   const float* __restrict__ bias,
                                                   float* __restrict__ out) {
  __shared__ unsigned short As[128 * 32];
  __shared__ unsigned short Bs[128 * 32];
  const int tid = threadIdx.x;
  const int wave = tid >> 6, lane = tid & 63;
  const int qd = lane >> 4, r = lane & 15;
  const int bm = blockIdx.x, bn = blockIdx.y;
  const int wr = (wave >> 1) * 64, wc = (wave & 1) * 64;

  f32x4 acc[4][4] = {};

  for (int k0 = 0; k0 < DM; k0 += 32) {
    __syncthreads();
#pragma unroll
    for (int p = 0; p < 2; p++) {
      int g = (wave * 2 + p) * 64 + lane;
      int row = g >> 2, ko = (g & 3) << 3;
      gld_lds16(A + (size_t)(bm * 128 + row) * DM + k0 + ko, &As[(wave * 2 + p) * 512]);
      gld_lds16(BT + (size_t)(bn * 128 + row) * DM + k0 + ko, &Bs[(wave * 2 + p) * 512]);
    }
    __syncthreads();

    short8 af[4], bfr[4];
#pragma unroll
    for (int mi = 0; mi < 4; mi++) af[mi] = *(const short8*)&As[(wr + mi * 16 + r) * 32 + qd * 8];
#pragma unroll
    for (int ni = 0; ni < 4; ni++) bfr[ni] = *(const short8*)&Bs[(wc + ni * 16 + r) * 32 + qd * 8];
#pragma unroll
    for (int mi = 0; mi < 4; mi++)
#pragma unroll
      for (int ni = 0; ni < 4; ni++) acc[mi][ni] = MFMA16(af[mi], bfr[ni], acc[mi][ni]);
  }

#pragma unroll
  for (int ni = 0; ni < 4; ni++) {
    int n = bn * 128 + wc + ni * 16 + r;
    float bvv = bias[n];
#pragma unroll
    for (int mi = 0; mi < 4; mi++) {
      int m0 = bm * 128 + wr + mi * 16 + qd * 4;
      f32x4 v = acc[mi][ni];
#pragma unroll
      for (int i = 0; i < 4; i++) out[(size_t)(m0 + i) * DM + n] = v[i] + bvv;
    }
  }
}

// ---------------- flash attention v6 = round-4 attn3 + exact-only tweaks ----------------
// (l-via-MFMA removed: empirically implicated in rounds 6/7 failures. fp32 lrun restored.)
// Q,K: [(b*H+h)*S + s][64] bf16 (Q pre-scaled by QSCALE); VT: [(b*H+h)*64 + d][S] bf16
// ctx out: [b*S+s][768] bf16
// 4 waves x 32 q. KVBLK=64. Ring-3 swizzled LDS bufs (48 KB), 1 barrier/tile.
// Iter t: QK^T(t) || [o*=scl(t-1) unless ==1; PV(t-1)] -> softmax(t) -> P-frags(t).
__global__ __launch_bounds__(256, 3) void attn6(const unsigned short* __restrict__ Q,
                                                const unsigned short* __restrict__ K,
                                                const unsigned short* __restrict__ VT,
                                                unsigned short* __restrict__ ctx) {
  __shared__ __align__(16) unsigned short sh[24576];  // 3 bufs x (K 4096 + V 4096) = 49152 B
  const int tid = threadIdx.x;
  const int w = tid >> 6, lane = tid & 63;
  const int ln = lane & 31, hi = lane >> 5;
  const int qt = blockIdx.x, h = blockIdx.y, b = blockIdx.z;
  const int bh = b * NH + h;
  const unsigned short* Qh = Q + (size_t)bh * SS * DHD;
  const unsigned short* Kh = K + (size_t)bh * SS * DHD;
  const unsigned short* Vh = VT + (size_t)bh * DHD * SS;
  const int q0 = qt * 128 + w * 32;

  // stage tile (64 keys): K 8KB + V 8KB, XOR-swizzled via pre-swizzled global src
  auto stage = [&](int kv, unsigned short* base) {
#pragma unroll
    for (int p = 0; p < 2; p++) {
      int g = ((w << 1) + p) * 64 + lane;
      int row = g >> 3, c = g & 7;
      int cs = (c ^ (row & 7)) << 3;
      gld_lds16(Kh + (size_t)(kv + row) * DHD + cs, base + (((w << 1) + p) << 9));
      gld_lds16(Vh + (size_t)row * SS + kv + cs, base + 4096 + (((w << 1) + p) << 9));
    }
  };

  // Q B-fragments: lane holds Q[q=ln][dh = kc*16 + hi*8 + j]
  short8 qf[4];
#pragma unroll
  for (int kc = 0; kc < 4; kc++)
    qf[kc] = *(const short8*)&Qh[(size_t)(q0 + ln) * DHD + kc * 16 + hi * 8];
#pragma unroll
  for (int kc = 0; kc < 4; kc++) asm volatile("" : "+v"(qf[kc]));

  unsigned short* bprev = sh + 16384;
  unsigned short* bcur = sh;
  unsigned short* bnxt = sh + 8192;

  stage(0, bcur);

  float mrun = -1e30f, lrun = 0.f, sclp = 0.f;
  f32x16 o0 = {}, o1 = {};
  f32x16 s0, s1;
  union PF { uint4v u; short8 s; };
  PF pf0, pf1, pf2, pf3;

  // QK^T into s0,s1 from K buffer
  auto qk = [&](const unsigned short* Kb) {
#pragma unroll
    for (int i = 0; i < 16; i++) { s0[i] = 0.f; s1[i] = 0.f; }
    __builtin_amdgcn_s_setprio(1);
#pragma unroll
    for (int kc = 0; kc < 4; kc++) {
      int sl = (((kc << 1) + hi) ^ (ln & 7)) << 3;
      s0 = MFMA32(*(const short8*)&Kb[(ln << 6) + sl], qf[kc], s0);
      s1 = MFMA32(*(const short8*)&Kb[((32 + ln) << 6) + sl], qf[kc], s1);
    }
    __builtin_amdgcn_s_setprio(0);
  };

  // rescale O (skipped when sclp==1.0 for all lanes: multiply-by-1 is an identity)
  // and accumulate PV of the PREVIOUS tile (pf*, V in Vb)
  auto pv = [&](const unsigned short* Vb) {
    if (!__all(sclp == 1.0f)) {
      o0 *= sclp;
      o1 *= sclp;
    }
    __builtin_amdgcn_s_setprio(1);
    {
      int sl0 = ((0 + hi) ^ (ln & 7)) << 3;
      int sl1 = ((2 + hi) ^ (ln & 7)) << 3;
      o0 = MFMA32(*(const short8*)&Vb[(ln << 6) + sl0], pf0.s, o0);
      o1 = MFMA32(*(const short8*)&Vb[((32 + ln) << 6) + sl0], pf0.s, o1);
      o0 = MFMA32(*(const short8*)&Vb[(ln << 6) + sl1], pf1.s, o0);
      o1 = MFMA32(*(const short8*)&Vb[((32 + ln) << 6) + sl1], pf1.s, o1);
    }
    {
      int sl0 = ((4 + hi) ^ (ln & 7)) << 3;
      int sl1 = ((6 + hi) ^ (ln & 7)) << 3;
      o0 = MFMA32(*(const short8*)&Vb[(ln << 6) + sl0], pf2.s, o0);
      o1 = MFMA32(*(const short8*)&Vb[((32 + ln) << 6) + sl0], pf2.s, o1);
      o0 = MFMA32(*(const short8*)&Vb[(ln << 6) + sl1], pf3.s, o0);
      o1 = MFMA32(*(const short8*)&Vb[((32 + ln) << 6) + sl1], pf3.s, o1);
    }
    __builtin_amdgcn_s_setprio(0);
  };

  // softmax on s0,s1 -> pf*, sclp, mrun, lrun (fp32 sum, as in the passing round-4 kernel)
  auto sm = [&]() {
    // exact max over the lane's 32 keys, max3-fusable tree
    float u0 = fmaxf(fmaxf(s0[0], s0[1]), s0[2]);
    float u1 = fmaxf(fmaxf(s0[3], s0[4]), s0[5]);
    float u2 = fmaxf(fmaxf(s0[6], s0[7]), s0[8]);
    float u3 = fmaxf(fmaxf(s0[9], s0[10]), s0[11]);
    float u4 = fmaxf(fmaxf(s0[12], s0[13]), s0[14]);
    float u5 = fmaxf(fmaxf(s0[15], s1[0]), s1[1]);
    float u6 = fmaxf(fmaxf(s1[2], s1[3]), s1[4]);
    float u7 = fmaxf(fmaxf(s1[5], s1[6]), s1[7]);
    float u8 = fmaxf(fmaxf(s1[8], s1[9]), s1[10]);
    float u9 = fmaxf(fmaxf(s1[11], s1[12]), s1[13]);
    float ua = fmaxf(s1[14], s1[15]);
    float v0 = fmaxf(fmaxf(u0, u1), u2);
    float v1 = fmaxf(fmaxf(u3, u4), u5);
    float v2 = fmaxf(fmaxf(u6, u7), u8);
    float v3 = fmaxf(u9, ua);
    float mx = fmaxf(fmaxf(v0, v1), fmaxf(v2, v3));
    mx = fmaxf(mx, __shfl_xor(mx, 32));
    float mn = fmaxf(mrun, mx);
    sclp = __builtin_amdgcn_exp2f(mrun - mn);
    mrun = mn;
#pragma unroll
    for (int i = 0; i < 16; i++) {
      s0[i] = __builtin_amdgcn_exp2f(s0[i] - mn);
      s1[i] = __builtin_amdgcn_exp2f(s1[i] - mn);
    }
    float a8[8];
#pragma unroll
    for (int i = 0; i < 8; i++) a8[i] = (s0[i] + s0[i + 8]) + (s1[i] + s1[i + 8]);
#pragma unroll
    for (int i = 0; i < 4; i++) a8[i] += a8[i + 4];
    float rs = (a8[0] + a8[1]) + (a8[2] + a8[3]);
    rs += __shfl_xor(rs, 32);
    lrun = lrun * sclp + rs;
    // P -> bf16 B-frags (cvt_pk + permlane32_swap). s reg r holds key (r&3)+8*(r>>2)+4*hi.
    {
      unsigned int w0, w1, w2, w3, w4, w5, w6, w7;
      CVTPK(w0, s0[0], s0[1]);   CVTPK(w1, s0[2], s0[3]);
      CVTPK(w2, s0[4], s0[5]);   CVTPK(w3, s0[6], s0[7]);
      CVTPK(w4, s0[8], s0[9]);   CVTPK(w5, s0[10], s0[11]);
      CVTPK(w6, s0[12], s0[13]); CVTPK(w7, s0[14], s0[15]);
      SWAP32(w0, w2); SWAP32(w1, w3); SWAP32(w4, w6); SWAP32(w5, w7);
      pf0.u = (uint4v){w0, w1, w2, w3};
      pf1.u = (uint4v){w4, w5, w6, w7};
    }
    {
      unsigned int w0, w1, w2, w3, w4, w5, w6, w7;
      CVTPK(w0, s1[0], s1[1]);   CVTPK(w1, s1[2], s1[3]);
      CVTPK(w2, s1[4], s1[5]);   CVTPK(w3, s1[6], s1[7]);
      CVTPK(w4, s1[8], s1[9]);   CVTPK(w5, s1[10], s1[11]);
      CVTPK(w6, s1[12], s1[13]); CVTPK(w7, s1[14], s1[15]);
      SWAP32(w0, w2); SWAP32(w1, w3); SWAP32(w4, w6); SWAP32(w5, w7);
      pf2.u = (uint4v){w0, w1, w2, w3};
      pf3.u = (uint4v){w4, w5, w6, w7};
    }
  };

  // ---- peeled iteration 0 ----
  asm volatile("s_waitcnt vmcnt(0)" ::: "memory");
  __builtin_amdgcn_s_barrier();
  stage(64, bnxt);
  qk(bcur);
  sm();
  { unsigned short* t = bprev; bprev = bcur; bcur = bnxt; bnxt = t; }

  // ---- main loop t = 1..63 ----
  for (int t = 1; t < SS / 64; t++) {
    asm volatile("s_waitcnt vmcnt(0)" ::: "memory");
    __builtin_amdgcn_s_barrier();
    if (t < SS / 64 - 1) stage((t + 1) << 6, bnxt);
    qk(bcur);
    pv(bprev + 4096);
    sm();
    { unsigned short* tp = bprev; bprev = bcur; bcur = bnxt; bnxt = tp; }
  }

  // tail: PV of last tile (its V is in bprev after final rotation)
  pv(bprev + 4096);

  // epilogue: O^T[d][q] -> ctx[b*S+sq][h*64+d]
  float inv = 1.0f / lrun;
  int sq = q0 + ln;
  unsigned short* cp = ctx + ((size_t)(b * SS + sq)) * DM + h * DHD;
#pragma unroll
  for (int q2 = 0; q2 < 4; q2++) {
    unsigned int pl, ph;
    CVTPK(pl, o0[q2 * 4 + 0] * inv, o0[q2 * 4 + 1] * inv);
    CVTPK(ph, o0[q2 * 4 + 2] * inv, o0[q2 * 4 + 3] * inv);
    uint2 st0; st0.x = pl; st0.y = ph;
    *(uint2*)(cp + q2 * 8 + hi * 4) = st0;
    CVTPK(pl, o1[q2 * 4 + 0] * inv, o1[q2 * 4 + 1] * inv);
    CVTPK(ph, o1[q2 * 4 + 2] * inv, o1[q2 * 4 + 3] * inv);
    uint2 st1; st1.x = pl; st1.y = ph;
    *(uint2*)(cp + 32 + q2 * 8 + hi * 4) = st1;
  }
}

// ---------------- launcher ----------------

extern "C" void kernel_launch(void* const* d_in, const int* in_sizes, int n_in,
                              void* d_out, int out_size, void* d_ws, size_t ws_size,
                              hipStream_t stream) {
  const float* hs = (const float*)d_in[0];
  const float* Wq = (const float*)d_in[1];
  const float* bq = (const float*)d_in[2];
  const float* Wk = (const float*)d_in[3];
  const float* bk = (const float*)d_in[4];
  const float* Wv = (const float*)d_in[5];
  const float* bv = (const float*)d_in[6];
  const float* Wo = (const float*)d_in[7];
  const float* bo = (const float*)d_in[8];

  char* ws = (char*)d_ws;
  unsigned short* Xbf = (unsigned short*)(ws + 0);           // 12.58 MB; later reused as ctx
  unsigned short* WqkvT = (unsigned short*)(ws + 12582912);  // 2304x768 + 768x768 bf16 (Wo contiguous)
  unsigned short* Qb = (unsigned short*)(ws + 17301504);     // 12.58 MB
  unsigned short* Kb = (unsigned short*)(ws + 29884416);     // 12.58 MB
  unsigned short* Vt = (unsigned short*)(ws + 42467328);     // 12.58 MB (end ~55.05 MB)
  unsigned short* WoT = WqkvT + 1769472;                     // = ws + 16121856

  convert_x<<<2048, 256, 0, stream>>>(hs, Xbf, MTOK * DM / 4);
  wtrans4<<<dim3(24, 24, 4), dim3(32, 8), 0, stream>>>(Wq, Wk, Wv, Wo, WqkvT);

  gemm_qkv<<<dim3(64, 18), 256, 0, stream>>>(Xbf, WqkvT, bq, bk, bv, Qb, Kb, Vt);

  attn6<<<dim3(32, NH, NB), 256, 0, stream>>>(Qb, Kb, Vt, Xbf);

  gemm_out<<<dim3(64, 6), 256, 0, stream>>>(Xbf, WoT, bo, (float*)d_out);
}